// Round 2
// baseline (541.824 us; speedup 1.0000x reference)
//
#include <hip/hip_runtime.h>
#include <hip/hip_bf16.h>

#define NN 8192
#define INF_ 512
#define OUTF 256

// ---------------- Kernel 1: Wh = h @ W  (fp32, 64x256 tile, 8x8/thread) ----
__global__ __launch_bounds__(256) void k_gemm_hW(const float* __restrict__ h,
                                                 const float* __restrict__ W,
                                                 float* __restrict__ Wh) {
  __shared__ float At[16][64];    // h^T tile
  __shared__ float Bt[16][256];   // W tile
  const int t = threadIdx.x;
  const int rb = blockIdx.x * 64;
  const int tr = t >> 5;          // 0..7 -> rows tr*8..tr*8+7
  const int tc = t & 31;          // 0..31
  const int sr = t >> 2;          // staging row 0..63
  const int sc = (t & 3) << 2;    // staging k offset 0,4,8,12
  float acc[8][8];
#pragma unroll
  for (int i = 0; i < 8; ++i)
#pragma unroll
    for (int j = 0; j < 8; ++j) acc[i][j] = 0.f;

  for (int kb = 0; kb < INF_; kb += 16) {
    float4 av = *reinterpret_cast<const float4*>(&h[(size_t)(rb + sr) * INF_ + kb + sc]);
    At[sc + 0][sr] = av.x;
    At[sc + 1][sr] = av.y;
    At[sc + 2][sr] = av.z;
    At[sc + 3][sr] = av.w;
    const float4* bsrc = reinterpret_cast<const float4*>(&W[(size_t)kb * OUTF]);
    float4* bdst = reinterpret_cast<float4*>(&Bt[0][0]);
#pragma unroll
    for (int p = 0; p < 4; ++p) bdst[p * 256 + t] = bsrc[p * 256 + t];
    __syncthreads();
#pragma unroll
    for (int k = 0; k < 16; ++k) {
      float a[8], b[8];
      *reinterpret_cast<float4*>(&a[0]) = *reinterpret_cast<const float4*>(&At[k][tr * 8]);
      *reinterpret_cast<float4*>(&a[4]) = *reinterpret_cast<const float4*>(&At[k][tr * 8 + 4]);
      *reinterpret_cast<float4*>(&b[0]) = *reinterpret_cast<const float4*>(&Bt[k][tc * 4]);
      *reinterpret_cast<float4*>(&b[4]) = *reinterpret_cast<const float4*>(&Bt[k][tc * 4 + 128]);
#pragma unroll
      for (int i = 0; i < 8; ++i)
#pragma unroll
        for (int j = 0; j < 8; ++j) acc[i][j] = fmaf(a[i], b[j], acc[i][j]);
    }
    __syncthreads();
  }
#pragma unroll
  for (int i = 0; i < 8; ++i) {
    float* dst = &Wh[(size_t)(rb + tr * 8 + i) * OUTF];
    *reinterpret_cast<float4*>(dst + tc * 4) = *reinterpret_cast<float4*>(&acc[i][0]);
    *reinterpret_cast<float4*>(dst + tc * 4 + 128) = *reinterpret_cast<float4*>(&acc[i][4]);
  }
}

// ---------------- Kernel 2: s/d per-row attention scalars ------------------
__global__ __launch_bounds__(256) void k_attn_sd(const float* __restrict__ Wh,
                                                 const float* __restrict__ a_src,
                                                 const float* __restrict__ a_dst,
                                                 float* __restrict__ sv,
                                                 float* __restrict__ dvv) {
  const int lane = threadIdx.x & 63;
  const int wave = threadIdx.x >> 6;
  const int row = blockIdx.x * 4 + wave;
  float4 wv = *reinterpret_cast<const float4*>(&Wh[(size_t)row * OUTF + lane * 4]);
  float4 as = *reinterpret_cast<const float4*>(&a_src[lane * 4]);
  float4 ad = *reinterpret_cast<const float4*>(&a_dst[lane * 4]);
  float ps = wv.x * as.x + wv.y * as.y + wv.z * as.z + wv.w * as.w;
  float pd = wv.x * ad.x + wv.y * ad.y + wv.z * ad.z + wv.w * ad.w;
#pragma unroll
  for (int off2 = 32; off2 > 0; off2 >>= 1) {
    ps += __shfl_down(ps, off2);
    pd += __shfl_down(pd, off2);
  }
  if (lane == 0) {
    sv[row] = ps;
    dvv[row] = pd;
  }
}

// ---------------- Kernel 3: fused mask+softmax(unnorm)+PV ------------------
// Output tile 64 rows x 256 cols per block, j-tiles of 32, j-split over
// blockIdx.y. Writes unnormalized partial acc + partial Z.
// No max-subtraction needed: e in +-~14, exp fits fp32 comfortably; masked
// entries are exactly 0 (reference's exp(-9e15 - m) underflows to 0 too).
__global__ __launch_bounds__(256) void k_attn_pv(const int* __restrict__ adj,
                                                 const float* __restrict__ Wh,
                                                 const float* __restrict__ sv,
                                                 const float* __restrict__ dv,
                                                 float* __restrict__ accP,
                                                 float* __restrict__ zP,
                                                 int jspan) {
  __shared__ float At[32][64];    // weight tile, transposed: At[j_local][row]
  __shared__ float Bt[32][256];   // Wh tile
  __shared__ float zred[64][4];
  const int t = threadIdx.x;
  const int rb = blockIdx.x * 64;
  const int tr = t >> 5;          // 0..7
  const int tc = t & 31;          // 0..31
  const int wr = t >> 2;          // weight-staging row 0..63
  const int wq = t & 3;           // j-quarter 0..3 (8 j's each)
  const float s_i = sv[rb + wr];
  float zacc = 0.f;
  float acc[8][8];
#pragma unroll
  for (int i = 0; i < 8; ++i)
#pragma unroll
    for (int j = 0; j < 8; ++j) acc[i][j] = 0.f;

  const int j0 = blockIdx.y * jspan;
  const int j1 = j0 + jspan;
  for (int jb = j0; jb < j1; jb += 32) {
    // ---- compute weight tile: w = adj ? exp(lrelu(s_i + d_j)) : 0 ----
    const int* arow = &adj[(size_t)(rb + wr) * NN + jb + wq * 8];
    int4 a0 = *reinterpret_cast<const int4*>(arow);
    int4 a1 = *reinterpret_cast<const int4*>(arow + 4);
    float4 d0 = *reinterpret_cast<const float4*>(&dv[jb + wq * 8]);
    float4 d1 = *reinterpret_cast<const float4*>(&dv[jb + wq * 8 + 4]);
    float dvals[8] = {d0.x, d0.y, d0.z, d0.w, d1.x, d1.y, d1.z, d1.w};
    int avals[8] = {a0.x, a0.y, a0.z, a0.w, a1.x, a1.y, a1.z, a1.w};
#pragma unroll
    for (int jj = 0; jj < 8; ++jj) {
      float e = s_i + dvals[jj];
      e = e >= 0.f ? e : 0.2f * e;
      float wv = avals[jj] > 0 ? expf(e) : 0.f;
      zacc += wv;
      At[wq * 8 + jj][wr] = wv;
    }
    // ---- stage Wh tile (rows jb..jb+32, contiguous) ----
    const float4* bsrc = reinterpret_cast<const float4*>(&Wh[(size_t)jb * OUTF]);
    float4* bdst = reinterpret_cast<float4*>(&Bt[0][0]);
#pragma unroll
    for (int p = 0; p < 8; ++p) bdst[p * 256 + t] = bsrc[p * 256 + t];
    __syncthreads();
    // ---- register-blocked FMA: acc += At^T x Bt ----
    // b-fragment cols {tc*4, tc*4+128}: 32 lanes read 512B contiguous ->
    // conflict-free LDS (vs tc*8 mapping: 32B stride, 16 banks, ~8-way).
#pragma unroll
    for (int jj = 0; jj < 32; ++jj) {
      float a[8], b[8];
      *reinterpret_cast<float4*>(&a[0]) = *reinterpret_cast<const float4*>(&At[jj][tr * 8]);
      *reinterpret_cast<float4*>(&a[4]) = *reinterpret_cast<const float4*>(&At[jj][tr * 8 + 4]);
      *reinterpret_cast<float4*>(&b[0]) = *reinterpret_cast<const float4*>(&Bt[jj][tc * 4]);
      *reinterpret_cast<float4*>(&b[4]) = *reinterpret_cast<const float4*>(&Bt[jj][tc * 4 + 128]);
#pragma unroll
      for (int i = 0; i < 8; ++i)
#pragma unroll
        for (int j = 0; j < 8; ++j) acc[i][j] = fmaf(a[i], b[j], acc[i][j]);
    }
    __syncthreads();
  }
  // ---- epilogue: partial acc + partial z ----
  zred[wr][wq] = zacc;
  __syncthreads();
  const size_t slab = (size_t)blockIdx.y * NN * OUTF;
#pragma unroll
  for (int i = 0; i < 8; ++i) {
    float* dst = &accP[slab + (size_t)(rb + tr * 8 + i) * OUTF];
    *reinterpret_cast<float4*>(dst + tc * 4) = *reinterpret_cast<float4*>(&acc[i][0]);
    *reinterpret_cast<float4*>(dst + tc * 4 + 128) = *reinterpret_cast<float4*>(&acc[i][4]);
  }
  if (t < 64) {
    zP[blockIdx.y * NN + rb + t] = zred[t][0] + zred[t][1] + zred[t][2] + zred[t][3];
  }
}

// ---------------- Kernel 4: combine partials, normalize --------------------
// Works in-place when accP == out (S==1 fallback).
__global__ __launch_bounds__(256) void k_reduce(const float* __restrict__ accP,
                                                const float* __restrict__ zP,
                                                float* __restrict__ out, int S) {
  const int row = blockIdx.x;
  const int f = threadIdx.x;
  const size_t idx = (size_t)row * OUTF + f;
  float a = 0.f, z = 0.f;
  for (int s = 0; s < S; ++s) {
    a += accP[(size_t)s * NN * OUTF + idx];
    z += zP[s * NN + row];
  }
  out[idx] = a / z;
}

extern "C" void kernel_launch(void* const* d_in, const int* in_sizes, int n_in,
                              void* d_out, int out_size, void* d_ws, size_t ws_size,
                              hipStream_t stream) {
  const float* h = (const float*)d_in[0];
  const int* adj = (const int*)d_in[1];
  const float* W = (const float*)d_in[2];
  const float* a_src = (const float*)d_in[3];
  const float* a_dst = (const float*)d_in[4];
  float* out = (float*)d_out;

  char* ws = (char*)d_ws;
  float* Wh = (float*)ws;                                   // 8 MB
  float* sv = (float*)(ws + (size_t)NN * OUTF * 4);         // 32 KB
  float* dvv = sv + NN;                                     // 32 KB
  float* zP = dvv + NN;                                     // up to 8*32 KB
  size_t off = (size_t)NN * OUTF * 4 + 2 * (size_t)NN * 4 + 8 * (size_t)NN * 4;
  off = (off + 255) & ~(size_t)255;
  const size_t slab_bytes = (size_t)NN * OUTF * 4;
  int S;
  float* accP;
  if (ws_size >= off + 8 * slab_bytes) { S = 8; accP = (float*)(ws + off); }
  else if (ws_size >= off + 4 * slab_bytes) { S = 4; accP = (float*)(ws + off); }
  else if (ws_size >= off + 2 * slab_bytes) { S = 2; accP = (float*)(ws + off); }
  else if (ws_size >= off + 1 * slab_bytes) { S = 1; accP = (float*)(ws + off); }
  else { S = 1; accP = out; }   // fallback: accumulate into out, normalize in place

  k_gemm_hW<<<dim3(NN / 64), dim3(256), 0, stream>>>(h, W, Wh);
  k_attn_sd<<<dim3(NN / 4), dim3(256), 0, stream>>>(Wh, a_src, a_dst, sv, dvv);
  k_attn_pv<<<dim3(NN / 64, S), dim3(256), 0, stream>>>(adj, Wh, sv, dvv, accP, zP, NN / S);
  k_reduce<<<dim3(NN), dim3(256), 0, stream>>>(accP, zP, out, S);
}

// Round 3
// 229.889 us; speedup vs baseline: 2.3569x; 2.3569x over previous
//
#include <hip/hip_runtime.h>
#include <hip/hip_bf16.h>

#define NN 8192
#define INF_ 512
#define OUTF 256

typedef __attribute__((ext_vector_type(8))) short short8;
typedef __attribute__((ext_vector_type(16))) float f32x16;

static __device__ __forceinline__ short f2bf(float x) {
  unsigned u = __float_as_uint(x);
  unsigned r = (u + 0x7fff + ((u >> 16) & 1)) >> 16;   // RNE to bf16
  return (short)r;
}
static __device__ __forceinline__ float bf2f(short s) {
  return __uint_as_float(((unsigned)(unsigned short)s) << 16);
}

// ---------------- Kernel 1: Wh = h @ W  (fp32, 64x256 tile, 8x8/thread) ----
__global__ __launch_bounds__(256) void k_gemm_hW(const float* __restrict__ h,
                                                 const float* __restrict__ W,
                                                 float* __restrict__ Wh) {
  __shared__ float At[16][64];
  __shared__ float Bt[16][256];
  const int t = threadIdx.x;
  const int rb = blockIdx.x * 64;
  const int tr = t >> 5;
  const int tc = t & 31;
  const int sr = t >> 2;
  const int sc = (t & 3) << 2;
  float acc[8][8];
#pragma unroll
  for (int i = 0; i < 8; ++i)
#pragma unroll
    for (int j = 0; j < 8; ++j) acc[i][j] = 0.f;

  for (int kb = 0; kb < INF_; kb += 16) {
    float4 av = *reinterpret_cast<const float4*>(&h[(size_t)(rb + sr) * INF_ + kb + sc]);
    At[sc + 0][sr] = av.x;
    At[sc + 1][sr] = av.y;
    At[sc + 2][sr] = av.z;
    At[sc + 3][sr] = av.w;
    const float4* bsrc = reinterpret_cast<const float4*>(&W[(size_t)kb * OUTF]);
    float4* bdst = reinterpret_cast<float4*>(&Bt[0][0]);
#pragma unroll
    for (int p = 0; p < 4; ++p) bdst[p * 256 + t] = bsrc[p * 256 + t];
    __syncthreads();
#pragma unroll
    for (int k = 0; k < 16; ++k) {
      float a[8], b[8];
      *reinterpret_cast<float4*>(&a[0]) = *reinterpret_cast<const float4*>(&At[k][tr * 8]);
      *reinterpret_cast<float4*>(&a[4]) = *reinterpret_cast<const float4*>(&At[k][tr * 8 + 4]);
      *reinterpret_cast<float4*>(&b[0]) = *reinterpret_cast<const float4*>(&Bt[k][tc * 4]);
      *reinterpret_cast<float4*>(&b[4]) = *reinterpret_cast<const float4*>(&Bt[k][tc * 4 + 128]);
#pragma unroll
      for (int i = 0; i < 8; ++i)
#pragma unroll
        for (int j = 0; j < 8; ++j) acc[i][j] = fmaf(a[i], b[j], acc[i][j]);
    }
    __syncthreads();
  }
#pragma unroll
  for (int i = 0; i < 8; ++i) {
    float* dst = &Wh[(size_t)(rb + tr * 8 + i) * OUTF];
    *reinterpret_cast<float4*>(dst + tc * 4) = *reinterpret_cast<float4*>(&acc[i][0]);
    *reinterpret_cast<float4*>(dst + tc * 4 + 128) = *reinterpret_cast<float4*>(&acc[i][4]);
  }
}

// ---------------- Kernel 1b: WhbT[col][row] = bf16(Wh[row][col]) -----------
__global__ __launch_bounds__(256) void k_transpose(const float* __restrict__ Wh,
                                                   short* __restrict__ WhbT) {
  __shared__ short tile[64][65];
  const int t = threadIdx.x;
  const int r0 = blockIdx.x * 64;   // rows
  const int c0 = blockIdx.y * 64;   // cols
  {
    const int ri = t >> 2, cq = t & 3;
    const float4* src = (const float4*)(Wh + (size_t)(r0 + ri) * OUTF + c0 + cq * 16);
#pragma unroll
    for (int q = 0; q < 4; ++q) {
      float4 v = src[q];
      int c = cq * 16 + q * 4;
      tile[ri][c + 0] = f2bf(v.x);
      tile[ri][c + 1] = f2bf(v.y);
      tile[ri][c + 2] = f2bf(v.z);
      tile[ri][c + 3] = f2bf(v.w);
    }
  }
  __syncthreads();
  {
    const int cj = t >> 2, rq = t & 3;
    short tmp[16];
#pragma unroll
    for (int q = 0; q < 16; ++q) tmp[q] = tile[rq * 16 + q][cj];
    short* dst = WhbT + (size_t)(c0 + cj) * NN + r0 + rq * 16;
    *(float4*)dst = *(float4*)&tmp[0];
    *(float4*)(dst + 8) = *(float4*)&tmp[8];
  }
}

// ---------------- Kernel 2: s/d per-row attention scalars ------------------
__global__ __launch_bounds__(256) void k_attn_sd(const float* __restrict__ Wh,
                                                 const float* __restrict__ a_src,
                                                 const float* __restrict__ a_dst,
                                                 float* __restrict__ sv,
                                                 float* __restrict__ dvv) {
  const int lane = threadIdx.x & 63;
  const int wave = threadIdx.x >> 6;
  const int row = blockIdx.x * 4 + wave;
  float4 wv = *reinterpret_cast<const float4*>(&Wh[(size_t)row * OUTF + lane * 4]);
  float4 as = *reinterpret_cast<const float4*>(&a_src[lane * 4]);
  float4 ad = *reinterpret_cast<const float4*>(&a_dst[lane * 4]);
  float ps = wv.x * as.x + wv.y * as.y + wv.z * as.z + wv.w * as.w;
  float pd = wv.x * ad.x + wv.y * ad.y + wv.z * ad.z + wv.w * ad.w;
#pragma unroll
  for (int off2 = 32; off2 > 0; off2 >>= 1) {
    ps += __shfl_down(ps, off2);
    pd += __shfl_down(pd, off2);
  }
  if (lane == 0) {
    sv[row] = ps;
    dvv[row] = pd;
  }
}

// ---------------- Kernel 3: fused mask+softmax(unnorm)+PV via MFMA ---------
// Block: 64 rows x 256 cols, 4 waves (each 32x128), K-step 64 over j-span.
// P tile computed on the fly into XOR-swizzled LDS; V = WhbT (bf16, K-major).
// Z accumulated from the bf16-ROUNDED weights so it matches MFMA operands.
__global__ __launch_bounds__(256) void k_attn_pv(const int* __restrict__ adj,
                                                 const short* __restrict__ WhbT,
                                                 const float* __restrict__ sv,
                                                 const float* __restrict__ dv,
                                                 float* __restrict__ accP,
                                                 float* __restrict__ zP,
                                                 int jspan) {
  __shared__ short Vt[256 * 64];   // [col][k], rows 128B, XOR-swizzled (32 KB)
  __shared__ short Pl[64 * 64];    // [row][k], rows 128B, XOR-swizzled (8 KB)
  __shared__ float zred[64][4];
  const int t = threadIdx.x;
  const int rb = blockIdx.x * 64;
  // P-gen mapping: thread -> (row pr, 16-wide j-chunk pq)
  const int pr = t >> 2;
  const int pq = t & 3;
  const float s_i = sv[rb + pr];
  // MFMA mapping
  const int lane = t & 63;
  const int wid = t >> 6;
  const int l31 = lane & 31;
  const int lhi = lane >> 5;
  const int wrow = (wid >> 1) * 32;   // 0 / 32
  const int wcol = (wid & 1) * 128;   // 0 / 128
  char* VtB = (char*)Vt;
  char* PlB = (char*)Pl;
  const int arow = wrow + l31;
  const int abase = arow * 128 + lhi * 16;
  const int aswz = (arow & 7) << 4;
  const int pbyte = pr * 128 + pq * 32;
  const int pswz = (pr & 7) << 4;
  const int vswz = (t & 7) << 4;

  f32x16 acc[4];
#pragma unroll
  for (int ct = 0; ct < 4; ++ct) acc[ct] = (f32x16)(0.f);
  float zacc = 0.f;

  const int j0 = blockIdx.y * jspan;
  for (int jb = j0; jb < j0 + jspan; jb += 64) {
    // ---- issue Vt staging loads early (col t, 64 k's = 128B contiguous) ----
    const float4* vsrc = (const float4*)(WhbT + (size_t)t * NN + jb);
    float4 sreg[8];
#pragma unroll
    for (int s = 0; s < 8; ++s) sreg[s] = vsrc[s];
    // ---- P-gen: w = adj ? exp(lrelu(s_i + d_j)) : 0, bf16-rounded ----
    const int* aptr = adj + (size_t)(rb + pr) * NN + jb + pq * 16;
    int4 a0 = ((const int4*)aptr)[0];
    int4 a1 = ((const int4*)aptr)[1];
    int4 a2 = ((const int4*)aptr)[2];
    int4 a3 = ((const int4*)aptr)[3];
    const float4* dptr = (const float4*)(dv + jb + pq * 16);
    float4 d0 = dptr[0], d1 = dptr[1], d2 = dptr[2], d3 = dptr[3];
    short wb[16];
#define PGEN(idx, aval, dval)                                 \
    {                                                         \
      float e = s_i + (dval);                                 \
      e = e >= 0.f ? e : 0.2f * e;                            \
      float w = ((aval) > 0) ? __expf(e) : 0.f;               \
      short b = f2bf(w);                                      \
      wb[idx] = b;                                            \
      zacc += bf2f(b);                                        \
    }
    PGEN(0, a0.x, d0.x) PGEN(1, a0.y, d0.y) PGEN(2, a0.z, d0.z) PGEN(3, a0.w, d0.w)
    PGEN(4, a1.x, d1.x) PGEN(5, a1.y, d1.y) PGEN(6, a1.z, d1.z) PGEN(7, a1.w, d1.w)
    PGEN(8, a2.x, d2.x) PGEN(9, a2.y, d2.y) PGEN(10, a2.z, d2.z) PGEN(11, a2.w, d2.w)
    PGEN(12, a3.x, d3.x) PGEN(13, a3.y, d3.y) PGEN(14, a3.z, d3.z) PGEN(15, a3.w, d3.w)
#undef PGEN
    *(float4*)(PlB + ((pbyte) ^ pswz)) = *(float4*)&wb[0];
    *(float4*)(PlB + ((pbyte + 16) ^ pswz)) = *(float4*)&wb[8];
    // ---- Vt writes (swizzled) ----
    {
      const int vbase = t * 128;
#pragma unroll
      for (int s = 0; s < 8; ++s)
        *(float4*)(VtB + ((vbase + s * 16) ^ vswz)) = sreg[s];
    }
    __syncthreads();
    // ---- MFMA: wave tile 32x128, 4 k-slices of 16 ----
#pragma unroll
    for (int ks = 0; ks < 4; ++ks) {
      short8 af = *(const short8*)(PlB + ((abase + ks * 32) ^ aswz));
#pragma unroll
      for (int ct = 0; ct < 4; ++ct) {
        const int c = wcol + ct * 32 + l31;
        short8 bf = *(const short8*)(VtB + ((c * 128 + ks * 32 + lhi * 16) ^ ((c & 7) << 4)));
        acc[ct] = __builtin_amdgcn_mfma_f32_32x32x16_bf16(af, bf, acc[ct], 0, 0, 0);
      }
    }
    __syncthreads();
  }
  // ---- epilogue ----
  zred[pr][pq] = zacc;
  __syncthreads();
  const size_t slab = (size_t)blockIdx.y * NN * OUTF;
#pragma unroll
  for (int ct = 0; ct < 4; ++ct) {
#pragma unroll
    for (int q = 0; q < 16; ++q) {
      const int row = rb + wrow + 4 * lhi + (q & 3) + 8 * (q >> 2);
      const int col = wcol + ct * 32 + l31;
      accP[slab + (size_t)row * OUTF + col] = acc[ct][q];
    }
  }
  if (t < 64) {
    zP[blockIdx.y * NN + rb + t] = zred[t][0] + zred[t][1] + zred[t][2] + zred[t][3];
  }
}

// ---------------- Kernel 4: combine partials, normalize --------------------
__global__ __launch_bounds__(256) void k_reduce(const float* __restrict__ accP,
                                                const float* __restrict__ zP,
                                                float* __restrict__ out, int S) {
  const int row = blockIdx.x;
  const int f = threadIdx.x;
  const size_t idx = (size_t)row * OUTF + f;
  float a = 0.f, z = 0.f;
  for (int s = 0; s < S; ++s) {
    a += accP[(size_t)s * NN * OUTF + idx];
    z += zP[s * NN + row];
  }
  out[idx] = a / z;
}

extern "C" void kernel_launch(void* const* d_in, const int* in_sizes, int n_in,
                              void* d_out, int out_size, void* d_ws, size_t ws_size,
                              hipStream_t stream) {
  const float* h = (const float*)d_in[0];
  const int* adj = (const int*)d_in[1];
  const float* W = (const float*)d_in[2];
  const float* a_src = (const float*)d_in[3];
  const float* a_dst = (const float*)d_in[4];
  float* out = (float*)d_out;

  char* ws = (char*)d_ws;
  float* Wh = (float*)ws;                                    // 8 MB
  short* WhbT = (short*)(ws + (size_t)NN * OUTF * 4);        // 4 MB
  float* sv = (float*)(ws + (size_t)NN * OUTF * 6);          // 32 KB
  float* dvv = sv + NN;                                      // 32 KB
  float* zP = dvv + NN;                                      // 4*32 KB
  size_t off = (size_t)NN * OUTF * 6 + 2 * (size_t)NN * 4 + 4 * (size_t)NN * 4;
  off = (off + 255) & ~(size_t)255;
  const size_t slab_bytes = (size_t)NN * OUTF * 4;
  int S;
  float* accP;
  if (ws_size >= off + 4 * slab_bytes) { S = 4; accP = (float*)(ws + off); }
  else if (ws_size >= off + 2 * slab_bytes) { S = 2; accP = (float*)(ws + off); }
  else if (ws_size >= off + 1 * slab_bytes) { S = 1; accP = (float*)(ws + off); }
  else { S = 1; accP = out; }   // fallback: accumulate into out, normalize in place

  k_gemm_hW<<<dim3(NN / 64), dim3(256), 0, stream>>>(h, W, Wh);
  k_transpose<<<dim3(NN / 64, OUTF / 64), dim3(256), 0, stream>>>(Wh, WhbT);
  k_attn_sd<<<dim3(NN / 4), dim3(256), 0, stream>>>(Wh, a_src, a_dst, sv, dvv);
  k_attn_pv<<<dim3(NN / 64, S), dim3(256), 0, stream>>>(adj, WhbT, sv, dvv, accP, zP, NN / S);
  k_reduce<<<dim3(NN), dim3(256), 0, stream>>>(accP, zP, out, S);
}